// Round 11
// baseline (25.864 us; speedup 1.0000x reference)
//
#include <hip/hip_runtime.h>
#include <stdint.h>

#define NR 5000
#define NRM1 4999
#define W 640
#define NBLK 2500          // block b: rows b and 4998-b == virtual space of 5000 elems
#define NTHR 128           // 128-thr blocks -> 16 blocks/CU -> 4096 capacity > 2500 (ONE wave)
#define NELEM 40           // per-thread elements: 40*128 = 5120 >= 5000
#define BATCH 20           // loads kept in flight per batch (VGPR budget)
#define PCOUNT 12497500.0f
#define LOG2E 1.44269504088896340736f
#define LN2   0.69314718055994530942f

// ---------------- Kernel 1: gather z = x[rows, cols] (once) ----------------
__global__ void gather_z(const float* __restrict__ x,
                         const int* __restrict__ centers,
                         float* __restrict__ z) {
    int t = blockIdx.x * blockDim.x + threadIdx.x;
    if (t < NR) {
        const int2 rc = ((const int2*)centers)[t];
        z[t] = x[rc.x * W + rc.y];
    }
}

// Virtual index v in [0,5000): c=min(v,vmax-1);
//   c < len1 : row1 (r=b):      gt[off1+c],  zj = z[b+1+c]
//   c >= len1: row2 (r=4998-b): gt[off2v+c], zj = z[c]      (j = r2+1+(c-len1) == c)
__global__ __launch_bounds__(NTHR) void pair_loss(const float* __restrict__ gt,
                                                  const float* __restrict__ z,
                                                  float* __restrict__ partials) {
    __shared__ float wsum[NTHR / 64];
    const int tid = threadIdx.x;
    const int b = blockIdx.x;

    const int r1 = b;
    const int r2 = NR - 2 - b;
    const int len1 = NRM1 - r1;                         // 4999-b
    const int off1 = r1 * NRM1 - (r1 * (r1 - 1)) / 2;   // fits i32
    const int off2 = r2 * NRM1 - (r2 * (r2 - 1)) / 2;
    const int off2v = off2 - len1;                      // virtual base for row2
    const int vmax = (r2 > r1) ? 5000 : len1;           // b==2499: single row of 2500
    const float zr1 = z[r1];
    const float zr2 = z[r2];

    float a0 = 0.0f, a1 = 0.0f, a2 = 0.0f, a3 = 0.0f;

    #pragma unroll
    for (int h = 0; h < NELEM / BATCH; ++h) {
        // ---- batch-issue BATCH independent gt loads (fully unrolled) ----
        float g[BATCH];
        #pragma unroll
        for (int k = 0; k < BATCH; ++k) {
            const int v = tid + NTHR * (h * BATCH + k);
            const int c = min(v, vmax - 1);             // clamp keeps addr in-bounds
            const int ofs = (c < len1) ? off1 : off2v;
            g[k] = gt[ofs + c];
        }
        // ---- consume: recompute indices (VALU-cheap), z via L1, 4 acc chains ----
        #pragma unroll
        for (int k = 0; k < BATCH; ++k) {
            const int v = tid + NTHR * (h * BATCH + k);
            const int c = min(v, vmax - 1);
            const bool row1 = c < len1;
            const float zj = z[c + (row1 ? r1 + 1 : 0)];
            const float zr = row1 ? zr1 : zr2;
            const float gg = g[k];
            const float d  = zr - zj;
            const float dl = d * LOG2E;
            const float lg = __log2f(1.0f + exp2f(-gg * dl));
            float l = (gg != 0.0f) ? lg : d * dl;       // g==0 -> d^2/ln2
            l = (v < vmax) ? l : 0.0f;                  // mask padding elems
            if      ((k & 3) == 0) a0 += l;
            else if ((k & 3) == 1) a1 += l;
            else if ((k & 3) == 2) a2 += l;
            else                   a3 += l;
        }
    }
    float acc = (a0 + a1) + (a2 + a3);

    // deterministic block reduction: wave shuffle tree + LDS across 2 waves
    for (int o = 32; o > 0; o >>= 1) acc += __shfl_down(acc, o, 64);
    if ((tid & 63) == 0) wsum[tid >> 6] = acc;
    __syncthreads();
    if (tid == 0)
        partials[b] = wsum[0] + wsum[1];
}

// ---------------- Kernel 3: deterministic final reduce (applies ln2/P) ----------------
__global__ __launch_bounds__(NTHR) void final_reduce(const float* __restrict__ partials,
                                                     float* __restrict__ out) {
    __shared__ float wsum[NTHR / 64];
    float acc = 0.0f;
    const float4* __restrict__ p4 = (const float4*)partials;   // 2500 = 625 float4s
    for (int t = threadIdx.x; t < NBLK / 4; t += NTHR) {
        const float4 v = p4[t];
        acc += (v.x + v.y) + (v.z + v.w);
    }
    for (int o = 32; o > 0; o >>= 1) acc += __shfl_down(acc, o, 64);
    if ((threadIdx.x & 63) == 0) wsum[threadIdx.x >> 6] = acc;
    __syncthreads();
    if (threadIdx.x == 0)
        out[0] = (wsum[0] + wsum[1]) * (LN2 / PCOUNT);
}

extern "C" void kernel_launch(void* const* d_in, const int* in_sizes, int n_in,
                              void* d_out, int out_size, void* d_ws, size_t ws_size,
                              hipStream_t stream) {
    const float* x       = (const float*)d_in[0];   // (480,640) f32
    const float* gt      = (const float*)d_in[1];   // (P,) f32
    const int*   centers = (const int*)d_in[2];     // (5000,2) int32
    float* out = (float*)d_out;                     // scalar f32

    float* z        = (float*)d_ws;                 // NR floats (16B-aligned)
    float* partials = z + NR;                       // NBLK floats

    gather_z<<<(NR + 255) / 256, 256, 0, stream>>>(x, centers, z);
    pair_loss<<<NBLK, NTHR, 0, stream>>>(gt, z, partials);
    final_reduce<<<1, NTHR, 0, stream>>>(partials, out);
}

// Round 12
// 25.215 us; speedup vs baseline: 1.0257x; 1.0257x over previous
//
#include <hip/hip_runtime.h>
#include <stdint.h>

#define NR 5000
#define NRM1 4999
#define W 640
#define NBLK 2500          // block b: rows b and 4998-b == virtual space of 5000 elems
#define NG 5               // float4 groups per thread: 5*4*256 = 5120 >= 5000
#define PCOUNT 12497500.0f
#define LOG2E 1.44269504088896340736f
#define LN2   0.69314718055994530942f

typedef float float4u __attribute__((ext_vector_type(4)));
struct __attribute__((packed, aligned(4))) f4wrap { float4u v; };

__device__ __forceinline__ float4u load4u(const float* p) {
    return ((const f4wrap*)p)->v;    // 4B-aligned vector load (HW-supported)
}

// ---------------- Kernel 1: gather z = x[rows, cols] (once) ----------------
__global__ void gather_z(const float* __restrict__ x,
                         const int* __restrict__ centers,
                         float* __restrict__ z) {
    int t = blockIdx.x * blockDim.x + threadIdx.x;
    if (t < NR) {
        const int2 rc = ((const int2*)centers)[t];
        z[t] = x[rc.x * W + rc.y];
    }
}

// Virtual index v in [0,vmax): v < len1 -> row1 (r=b):      gt[off1+v],  zj=z[b+1+v]
//                              v >= len1 -> row2 (r=4998-b): gt[off2v+v], zj=z[v]
// vmax is 5000 (or 2500 for b==2499) -> divisible by 4, so 4-elem groups are
// never partial: each group is fully valid or fully padding (clamped+masked).
__global__ __launch_bounds__(256) void pair_loss(const float* __restrict__ gt,
                                                 const float* __restrict__ z,
                                                 float* __restrict__ partials) {
    __shared__ float sz[NR];        // 20000 B -> 8 blocks/CU
    __shared__ float wsum[4];
    const int tid = threadIdx.x;
    const int b = blockIdx.x;

    const float4* __restrict__ zf4 = (const float4*)z;
    for (int t = tid; t < NR / 4; t += 256)
        *(float4*)&sz[4 * t] = zf4[t];
    __syncthreads();

    const int r1 = b, r2 = NR - 2 - b;
    const int len1 = NRM1 - r1;                         // 4999-b
    const int off1 = r1 * NRM1 - (r1 * (r1 - 1)) / 2;   // fits i32
    const int off2 = r2 * NRM1 - (r2 * (r2 - 1)) / 2;
    const int off2v = off2 - len1;
    const int vmax = (r2 > r1) ? 5000 : len1;           // both multiples of 4
    const float zr1 = sz[r1], zr2 = sz[r2];

    // ---- batch-issue NG float4 gt loads (independent, fully unrolled) ----
    float4u g4[NG];
    int cb[NG];
    #pragma unroll
    for (int k = 0; k < NG; ++k) {
        const int vb = 4 * tid + 1024 * k;
        const int c = min(vb, vmax - 4);                // clamp keeps addr in-bounds
        cb[k] = c;
        const float* base = (c < len1) ? (gt + off1) : (gt + off2v);
        g4[k] = load4u(base + c);
    }
    // straddle fixup: a group spanning the row1/row2 junction loaded its row2
    // elements from the wrong base; reload those (<=1 lane per wave-group).
    #pragma unroll
    for (int k = 0; k < NG; ++k) {
        const int c = cb[k];
        if (c < len1 && c + 3 >= len1) {
            #pragma unroll
            for (int e = 0; e < 4; ++e)
                if (c + e >= len1) g4[k][e] = gt[off2v + c + e];
        }
    }

    // ---- consume: z from LDS, lean log2-domain loss, 4 acc chains ----
    float a0 = 0.0f, a1 = 0.0f, a2 = 0.0f, a3 = 0.0f;
    #pragma unroll
    for (int k = 0; k < NG; ++k) {
        const int c = cb[k];
        float l[4];
        #pragma unroll
        for (int e = 0; e < 4; ++e) {
            const int ce = c + e;
            const bool in1 = ce < len1;
            const float zj = sz[ce + (in1 ? r1 + 1 : 0)];
            const float zr = in1 ? zr1 : zr2;
            const float g = g4[k][e];
            const float s  = zj - zr;                   // -d
            const float sl = s * LOG2E;
            const float lg = __log2f(1.0f + exp2f(g * sl));  // softplus(-g*d)/ln2
            l[e] = (g != 0.0f) ? lg : s * sl;           // g==0 -> d^2/ln2
        }
        const float gs = (l[0] + l[1]) + (l[2] + l[3]);
        const float gv = (4 * tid + 1024 * k < vmax) ? gs : 0.0f;  // per-GROUP mask
        if      ((k & 3) == 0) a0 += gv;
        else if ((k & 3) == 1) a1 += gv;
        else if ((k & 3) == 2) a2 += gv;
        else                   a3 += gv;
    }
    float acc = (a0 + a1) + (a2 + a3);

    // deterministic block reduction: wave shuffle tree + LDS across 4 waves
    for (int o = 32; o > 0; o >>= 1) acc += __shfl_down(acc, o, 64);
    if ((tid & 63) == 0) wsum[tid >> 6] = acc;
    __syncthreads();
    if (tid == 0)
        partials[b] = (wsum[0] + wsum[1]) + (wsum[2] + wsum[3]);
}

// ---------------- Kernel 3: deterministic final reduce (applies ln2/P) ----------------
__global__ __launch_bounds__(256) void final_reduce(const float* __restrict__ partials,
                                                    float* __restrict__ out) {
    __shared__ float wsum[4];
    float acc = 0.0f;
    const float4* __restrict__ p4 = (const float4*)partials;   // 2500 = 625 float4s
    for (int t = threadIdx.x; t < NBLK / 4; t += 256) {
        const float4 v = p4[t];
        acc += (v.x + v.y) + (v.z + v.w);
    }
    for (int o = 32; o > 0; o >>= 1) acc += __shfl_down(acc, o, 64);
    if ((threadIdx.x & 63) == 0) wsum[threadIdx.x >> 6] = acc;
    __syncthreads();
    if (threadIdx.x == 0)
        out[0] = ((wsum[0] + wsum[1]) + (wsum[2] + wsum[3])) * (LN2 / PCOUNT);
}

extern "C" void kernel_launch(void* const* d_in, const int* in_sizes, int n_in,
                              void* d_out, int out_size, void* d_ws, size_t ws_size,
                              hipStream_t stream) {
    const float* x       = (const float*)d_in[0];   // (480,640) f32
    const float* gt      = (const float*)d_in[1];   // (P,) f32
    const int*   centers = (const int*)d_in[2];     // (5000,2) int32
    float* out = (float*)d_out;                     // scalar f32

    float* z        = (float*)d_ws;                 // NR floats (16B-aligned)
    float* partials = z + NR;                       // NBLK floats

    gather_z<<<(NR + 255) / 256, 256, 0, stream>>>(x, centers, z);
    pair_loss<<<NBLK, 256, 0, stream>>>(gt, z, partials);
    final_reduce<<<1, 256, 0, stream>>>(partials, out);
}